// Round 10
// baseline (8971.610 us; speedup 1.0000x reference)
//
#include <hip/hip_runtime.h>

// ESN recurrence on MI355X: h_t = tanh(x_t @ W_in^T + h_{t-1} @ W_res^T)
// B=64, T=512, I=128, H=2048. Persistent kernel, 256 WGs (1/CU).
//
// R17 = R16 + LAUNCH FALLBACK. R15 and R16 failed with IDENTICAL absmax
// (deterministic, schedule-independent) and error == exactly 1.0 == max|ref|
// vs a memset-0 output => the kernel never executed. hipLaunchCooperativeKernel's
// return was never checked; at ~400 VGPRs (big-VGPR mode, >256) the coop
// co-residency occupancy check plausibly computes 0 blocks/CU (pre-big-VGPR
// model: floor(256/VGPR)=0) and rejects the grid. R5's 80-VGPR kernel passed
// the same check. Fix: check the return; on failure use a plain launch —
// co-residency holds structurally (grid = 256 = #CUs, >=1 WG/CU always).
//
// Kernel body identical to R16 (XCD-local retile + rule-#18 sched_barriers):
//  - 8 bgs x 8 batches, bg = wg&7 => all 32 WGs of a bg on ONE XCD (heuristic).
//  - W_res slice in VGPRs (bw[64] f16x8 = 256 VGPR); MFMA swapped
//    D[m=col][n=batch] = W_res(A) x h(B); no barriers in the t-loop.
//  - In-band fp16-LSB tags = truth; sc0 fast-path loads; escalation
//    (rounds>=6: acquire-agent fence (buffer_inv) + sc0 sc1 loads) guarantees
//    progress and evicts poisoned L2 lines (h_{t-4} tag-collision safe:
//    L3 is monotone h_t/h_{t-2} and h_{t-2}'s tag always mismatches).

#define B_ 64
#define T_ 512
#define I_ 128
#define H_ 2048
#define NWG 256
#define ROWS 64          // output cols per WG
#define BATS 8           // batches per WG
#define IPAD 136         // 128 + 8 halves row pad (Win staging)

typedef _Float16 f16;
typedef f16 f16x8 __attribute__((ext_vector_type(8)));
typedef float f32x4 __attribute__((ext_vector_type(4)));
typedef unsigned long long u64;
typedef unsigned int u32;
typedef unsigned short u16;
typedef u32 u32x4 __attribute__((ext_vector_type(4)));

#define TAG32 0x00010001u            // fp16 mantissa-LSB tag, 2 halves per dword

// 8 x dwordx4 loads for k-group g (ks = g*8 .. g*8+7), each 16B at stride 64B.
#define HLOAD(W, g, BITS) do {                                                 \
    _Pragma("unroll")                                                          \
    for (int _i = 0; _i < 8; _i++)                                             \
        asm volatile("global_load_dwordx4 %0, %1, off " BITS                   \
                     : "=&v"(W[_i]) : "v"(hb + (u64)(((g) * 8 + _i) * 64)));   \
} while (0)

// wait -> SCHED_BARRIER (rule #18) -> validate(retry ladder) -> 8 MFMAs
// -> prefetch g+2 into the same register window.
#define GPROC(g, W, NWAIT, DO_ISSUE) do {                                      \
    asm volatile("s_waitcnt vmcnt(" #NWAIT ")" ::: "memory");                  \
    __builtin_amdgcn_sched_barrier(0);                                         \
    int rounds_ = 0;                                                           \
    for (;;) {                                                                 \
        u32 bad_ = 0;                                                          \
        _Pragma("unroll")                                                      \
        for (int _i = 0; _i < 8; _i++) {                                       \
            bad_ |= (W[_i][0] & TAG32) ^ E32;   /* u64 store #0 */             \
            bad_ |= (W[_i][2] & TAG32) ^ E32;   /* u64 store #1 */             \
        }                                                                      \
        if (__all(bad_ == 0)) break;                                           \
        ++rounds_;                                                             \
        __builtin_amdgcn_s_sleep(1);                                           \
        if (rounds_ < 6) {                                                     \
            HLOAD(W, g, "sc0");                 /* L2-cached retry */          \
        } else {                                                               \
            __builtin_amdgcn_fence(__ATOMIC_ACQUIRE, "agent");                 \
            HLOAD(W, g, "sc0 sc1");             /* guaranteed: L3 direct */    \
        }                                                                      \
        asm volatile("s_waitcnt vmcnt(0)" ::: "memory");                       \
        __builtin_amdgcn_sched_barrier(0);                                     \
    }                                                                          \
    _Pragma("unroll")                                                          \
    for (int _i = 0; _i < 8; _i++) {                                           \
        f16x8 hf_;                                                             \
        _Pragma("unroll")                                                      \
        for (int _e = 0; _e < 4; _e++)                                         \
            ((u32*)&hf_)[_e] = W[_i][_e] & ~TAG32;   /* clear tag (<=1 ulp) */ \
        acc[(g) & 3] = __builtin_amdgcn_mfma_f32_16x16x32_f16(                 \
            bw[(g) * 8 + _i], hf_, acc[(g) & 3], 0, 0, 0);                     \
    }                                                                          \
    if (DO_ISSUE) HLOAD(W, (g) + 2, "sc0");                                    \
} while (0)

extern "C" __global__ __launch_bounds__(256, 1)
void esn_kernel(const float* __restrict__ x, const float* __restrict__ Win,
                const float* __restrict__ Wres, float* __restrict__ out,
                u16* ht0, u16* ht1)
{
    __shared__ f16 Whi[ROWS][IPAD];   // W_in hi (fp16)
    __shared__ f16 Wlo[ROWS][IPAD];   // W_in lo (precision split)

    const int tid  = threadIdx.x;
    const int wg   = blockIdx.x;
    const int bg   = wg & 7;          // batch group == XCD id (heuristic)
    const int j    = wg >> 3;         // 0..31 row-group on this XCD
    const int r0   = j * ROWS;        // col base
    const int b0   = bg * BATS;       // batch base
    const int wv   = tid >> 6;        // wave 0..3 (owns cols r0+wv*16..+16)
    const int lane = tid & 63;
    const int lm   = lane & 15;       // A: m(col) idx / B,D: n(batch) idx
    const int quad = lane >> 4;       // k sub-chunk / D row group
    const int lm8  = lm & 7;          // valid batch (lanes lm>=8 replicate)

    // ---- one-time: W_in slice as fp16 hi+lo into LDS ----
    for (int idx = tid; idx < ROWS * (I_ / 4); idx += 256) {
        int r  = idx >> 5;            // 32 float4 per row
        int c4 = idx & 31;
        const float4 v = ((const float4*)(Win + (size_t)(r0 + r) * I_))[c4];
        float vv[4] = {v.x, v.y, v.z, v.w};
        #pragma unroll
        for (int q = 0; q < 4; q++) {
            f16 hi = (f16)vv[q];
            Whi[r][c4 * 4 + q] = hi;
            Wlo[r][c4 * 4 + q] = (f16)(vv[q] - (float)hi);
        }
    }
    __syncthreads();

    // ---- one-time: W_res A-fragments (fp32 -> fp16) into VGPRs ----
    // Lane (lm,quad) of wave wv holds W_res[r0+wv*16+lm][ks*32+quad*8 ..+8]
    // for ks = 0..63  => 256 VGPRs/lane, constant across all t.
    f16x8 bw[64];
    {
        const float* wp = Wres + (size_t)(r0 + wv * 16 + lm) * H_ + quad * 8;
        #pragma unroll
        for (int ks = 0; ks < 64; ks++) {
            float4 p0 = *(const float4*)(wp + ks * 32);
            float4 p1 = *(const float4*)(wp + ks * 32 + 4);
            f16x8 b;
            b[0] = (f16)p0.x; b[1] = (f16)p0.y; b[2] = (f16)p0.z; b[3] = (f16)p0.w;
            b[4] = (f16)p1.x; b[5] = (f16)p1.y; b[6] = (f16)p1.z; b[7] = (f16)p1.w;
            bw[ks] = b;
        }
    }

    f32x4 acc[4];

    for (int t = 0; t < T_; t++) {
        const u16* hrd = (t & 1) ? ht1 : ht0;   // fresh data carries bit (t>>1)&1
        u16*       hwr = (t & 1) ? ht0 : ht1;   // write h_{t+1}, bit ((t+1)>>1)&1
        const u32  E32 = ((t >> 1) & 1) ? TAG32 : 0u;

        #pragma unroll
        for (int q = 0; q < 4; q++) acc[q] = (f32x4){0.f, 0.f, 0.f, 0.f};

        // lane's h row base (bytes): batch row 4096B, quad sub-chunk 16B
        const u64 hb = (u64)hrd + ((u64)(b0 + lm8) << 12) + (quad << 4);

        // speculative prefetch of k-groups 0,1 (tags are the truth; if the
        // producers already stored, these hit fresh L2 and validate clean)
        u32x4 w0[8], w1[8];
        HLOAD(w0, 0, "sc0");
        HLOAD(w1, 1, "sc0");

        // ---- x_t part: D[col][batch] += Win(A) x x(B), hi/lo split ----
        {
            const float* xp  = x + ((size_t)(b0 + lm8) * T_ + t) * I_ + quad * 8;
            const f16*   whp = &Whi[wv * 16 + lm][quad * 8];
            const f16*   wlp = &Wlo[wv * 16 + lm][quad * 8];
            #pragma unroll
            for (int k4 = 0; k4 < 4; k4++) {
                float xf[8];
                *(float4*)(xf)     = *(const float4*)(xp + k4 * 32);
                *(float4*)(xf + 4) = *(const float4*)(xp + k4 * 32 + 4);
                f16x8 xhi, xlo;
                #pragma unroll
                for (int q = 0; q < 8; q++) {
                    f16 hi = (f16)xf[q];
                    xhi[q] = hi;
                    xlo[q] = (f16)(xf[q] - (float)hi);
                }
                f16x8 wh = *(const f16x8*)(whp + k4 * 32);
                f16x8 wl = *(const f16x8*)(wlp + k4 * 32);
                acc[k4] = __builtin_amdgcn_mfma_f32_16x16x32_f16(wh, xhi, acc[k4], 0, 0, 0);
                acc[k4] = __builtin_amdgcn_mfma_f32_16x16x32_f16(wh, xlo, acc[k4], 0, 0, 0);
                acc[k4] = __builtin_amdgcn_mfma_f32_16x16x32_f16(wl, xhi, acc[k4], 0, 0, 0);
            }
        }

        // ---- h_{t-1} @ W_res^T: 8 k-groups, 2-deep load pipeline ----
        GPROC(0, w0, 8, 1);
        GPROC(1, w1, 8, 1);
        GPROC(2, w0, 8, 1);
        GPROC(3, w1, 8, 1);
        GPROC(4, w0, 8, 1);
        GPROC(5, w1, 8, 1);
        GPROC(6, w0, 8, 0);
        GPROC(7, w1, 0, 0);

        const f32x4 s = (acc[0] + acc[1]) + (acc[2] + acc[3]);

        // lane (lm<8) holds batch b0+lm, cols r0+wv*16+quad*4 ..+4 (contiguous)
        if (t == T_ - 1) {
            if (lm < 8) {
                float4 o;
                o.x = tanhf(s[0]); o.y = tanhf(s[1]);
                o.z = tanhf(s[2]); o.w = tanhf(s[3]);
                *(float4*)(out + (size_t)(b0 + lm) * H_ + r0 + wv * 16 + quad * 4) = o;
            }
        } else if (lm < 8) {
            const u16 bit = (u16)(((t + 1) >> 1) & 1);
            union { u16 h[4]; u64 u; } pk;
            #pragma unroll
            for (int e = 0; e < 4; e++) {
                union { f16 f; u16 u; } cv;
                cv.f = (f16)tanhf(s[e]);
                pk.h[e] = (u16)((cv.u & 0xFFFEu) | bit);   // mantissa LSB = tag
            }
            // agent write-through: updates local L2 (fast path for same-XCD
            // consumers) AND lands at L3 (guaranteed path for escalation)
            __hip_atomic_store((u64*)(hwr + (size_t)(b0 + lm) * H_ + r0 + wv * 16 + quad * 4),
                               pk.u, __ATOMIC_RELAXED, __HIP_MEMORY_SCOPE_AGENT);
        }
        // no barriers: waves are fully independent within a step; ordering is
        // enforced by the tag protocol (a consumer passes validation only
        // after every producer wave finished reading the previous buffer).
    }
}

extern "C" void kernel_launch(void* const* d_in, const int* in_sizes, int n_in,
                              void* d_out, int out_size, void* d_ws, size_t ws_size,
                              hipStream_t stream)
{
    (void)in_sizes; (void)n_in; (void)out_size; (void)ws_size;
    const float* x    = (const float*)d_in[0];
    const float* Win  = (const float*)d_in[1];
    const float* Wres = (const float*)d_in[2];
    float* out = (float*)d_out;

    u16* ht0 = (u16*)d_ws;                        // [64][2048] fp16, LSB = tag
    u16* ht1 = ht0 + (size_t)B_ * H_;

    // buffer0: 0x00 -> h_0 = 0, tag 0 fresh for t=0; buffer1: 0x01 -> stale
    // (LSB=1 != expected 0) until real h_1 is stored.
    hipMemsetAsync(d_ws, 0x00, (size_t)B_ * H_ * sizeof(u16), stream);
    hipMemsetAsync((char*)d_ws + (size_t)B_ * H_ * sizeof(u16), 0x01,
                   (size_t)B_ * H_ * sizeof(u16), stream);

    void* args[] = {(void*)&x, (void*)&Win, (void*)&Wres, (void*)&out,
                    (void*)&ht0, (void*)&ht1};
    // Coop launch guarantees co-residency; at >256 VGPRs (big-VGPR mode) the
    // runtime's coop occupancy check may spuriously reject (R15/R16: silent
    // zero-output failure, return never checked). Fall back to a plain launch:
    // grid = 256 = #CUs and any valid kernel gets >=1 WG/CU, so all WGs are
    // co-resident anyway.
    hipError_t ce = hipLaunchCooperativeKernel((const void*)esn_kernel,
                                               dim3(NWG), dim3(256),
                                               args, 0, stream);
    if (ce != hipSuccess) {
        hipLaunchKernelGGL(esn_kernel, dim3(NWG), dim3(256), 0, stream,
                           x, Win, Wres, out, ht0, ht1);
    }
}

// Round 12
// 2495.045 us; speedup vs baseline: 3.5958x; 3.5958x over previous
//
#include <hip/hip_runtime.h>

// ESN recurrence on MI355X: h_t = tanh(x_t @ W_in^T + h_{t-1} @ W_res^T)
// B=64, T=512, I=128, H=2048. Persistent cooperative kernel, 256 WGs (1/CU).
// Logical WG (bg,j): batches [bg*16,+16), rows [j*32,+32).
// R18 = R14 REVERT (verified 2477us, R5 counters) + coop-launch return check.
// R15-R17 (XCD-local retile, W_res in VGPRs) is REFUTED by R10 counters:
// VGPR_Count=208 < 256 needed => bw[] spilled to scratch; 5x run variance
// => retry storms without the flag-hint spin; FETCH never collapsed. Reverting
// to the known-good lineage: XCD-local h caching via leader buffer_inv,
// in-band fp16-LSB tags = truth, flag hints = detection, halved dword{0,2}
// tag validation (staleness granularity = producer's u64 atomic store).

#define B_ 64
#define T_ 512
#define I_ 128
#define H_ 2048
#define NWG 256
#define ROWS 32          // output rows per WG
#define BATS 16          // batches per WG
#define WPAD 2056        // 2048 + 8 halves row pad
#define IPAD 136         // 128 + 8 halves row pad
#define PPAD 33          // partial row pad (break 32-bank stride)
#define FSTRIDE 16       // flag stride in dwords (64 B line per producer)

typedef _Float16 f16;
typedef f16 f16x8 __attribute__((ext_vector_type(8)));
typedef float f32x4 __attribute__((ext_vector_type(4)));
typedef unsigned long long u64;
typedef unsigned int u32;
typedef unsigned short u16;
typedef u32 u32x4 __attribute__((ext_vector_type(4)));

#define TAG32 0x00010001u            // mantissa-LSB mask, 2 halves per dword

// LDS layout (bytes):
//   Wres  : ROWS*WPAD*2           = 131584
//   Win_hi: ROWS*IPAD*2           =   8704
//   Win_lo: ROWS*IPAD*2           =   8704
//   part  : 4*BATS*PPAD*4         =   8448
#define LDS_WRES   0
#define LDS_WINHI  131584
#define LDS_WINLO  (131584 + 8704)
#define LDS_PART   (131584 + 17408)
#define LDS_TOTAL  (131584 + 17408 + 8448)

extern "C" __global__ __launch_bounds__(256, 1)
void esn_kernel(const float* __restrict__ x, const float* __restrict__ Win,
                const float* __restrict__ Wres, float* __restrict__ out,
                u16* ht0, u16* ht1, int* flags)
{
    extern __shared__ char lds[];
    f16*   Wr   = (f16*)(lds + LDS_WRES);    // [ROWS][WPAD]
    f16*   Whi  = (f16*)(lds + LDS_WINHI);   // [ROWS][IPAD]
    f16*   Wlo  = (f16*)(lds + LDS_WINLO);   // [ROWS][IPAD]
    float* part = (float*)(lds + LDS_PART);  // [4][BATS][PPAD]

    const int tid  = threadIdx.x;
    const int wg   = blockIdx.x;
    // XCD-aware remap (XCD = wg&7 assumed): bg's 64 WGs sit on XCDs {2bg,2bg+1}
    const int bg   = (wg & 7) >> 1;             // batch group 0..3
    const int j    = ((wg >> 3) << 1) | (wg & 1); // row group 0..63
    const int lid  = (bg << 6) | j;             // logical id (flag index)
    const bool leader = (wg < 8);               // one WG per XCD (under the map)
    const int r0   = j * ROWS;
    const int b0   = bg * BATS;
    const int wv   = tid >> 6;      // wave 0..3
    const int lane = tid & 63;
    const int lm   = lane & 15;     // A: m index / B: n index / C: col index
    const int quad = lane >> 4;     // 0..3

    // ---- one-time init: stage W_res slice (fp32 -> fp16) into LDS ----
    for (int idx = tid; idx < ROWS * (H_ / 4); idx += 256) {
        int r  = idx >> 9;          // 512 float4 per row
        int c4 = idx & 511;
        const float4 v = ((const float4*)(Wres + (size_t)(r0 + r) * H_))[c4];
        f16* dst = Wr + r * WPAD + c4 * 4;
        dst[0] = (f16)v.x; dst[1] = (f16)v.y; dst[2] = (f16)v.z; dst[3] = (f16)v.w;
    }
    // ---- W_in slice as fp16 hi + lo (precision split) ----
    for (int idx = tid; idx < ROWS * (I_ / 4); idx += 256) {
        int r  = idx >> 5;          // 32 float4 per row
        int c4 = idx & 31;
        const float4 v = ((const float4*)(Win + (size_t)(r0 + r) * I_))[c4];
        float vv[4] = {v.x, v.y, v.z, v.w};
        f16* dh = Whi + r * IPAD + c4 * 4;
        f16* dl = Wlo + r * IPAD + c4 * 4;
        #pragma unroll
        for (int q = 0; q < 4; q++) {
            f16 hi = (f16)vv[q];
            dh[q] = hi;
            dl[q] = (f16)(vv[q] - (float)hi);
        }
    }
    __syncthreads();

    for (int t = 0; t < T_; t++) {
        const u16* hrd = (t & 1) ? ht1 : ht0;   // fresh data carries bit (t>>1)&1
        u16*       hwr = (t & 1) ? ht0 : ht1;   // write h_{t+1}, bit ((t+1)>>1)&1
        const u32  E32 = ((t >> 1) & 1) ? TAG32 : 0u;

        f32x4 acc0 = {0.f, 0.f, 0.f, 0.f};
        f32x4 acc1 = {0.f, 0.f, 0.f, 0.f};

        // ---- x_t @ W_in^T with fp16 hi/lo split (before the wait) ----
        {
            const int kin = wv * 32 + quad * 8;
            const float* xp = x + ((size_t)(b0 + lm) * T_ + t) * I_ + kin;
            float xf[8];
            *(float4*)(xf)     = *(const float4*)(xp);
            *(float4*)(xf + 4) = *(const float4*)(xp + 4);
            f16x8 xhi, xlo;
            #pragma unroll
            for (int qq = 0; qq < 8; qq++) {
                f16 hi = (f16)xf[qq];
                xhi[qq] = hi;
                xlo[qq] = (f16)(xf[qq] - (float)hi);
            }
            f16x8 bh0 = *(const f16x8*)(Whi + lm * IPAD + kin);
            f16x8 bh1 = *(const f16x8*)(Whi + (lm + 16) * IPAD + kin);
            f16x8 bl0 = *(const f16x8*)(Wlo + lm * IPAD + kin);
            f16x8 bl1 = *(const f16x8*)(Wlo + (lm + 16) * IPAD + kin);
            acc0 = __builtin_amdgcn_mfma_f32_16x16x32_f16(xhi, bh0, acc0, 0, 0, 0);
            acc1 = __builtin_amdgcn_mfma_f32_16x16x32_f16(xhi, bh1, acc1, 0, 0, 0);
            acc0 = __builtin_amdgcn_mfma_f32_16x16x32_f16(xlo, bh0, acc0, 0, 0, 0);
            acc1 = __builtin_amdgcn_mfma_f32_16x16x32_f16(xlo, bh1, acc1, 0, 0, 0);
            acc0 = __builtin_amdgcn_mfma_f32_16x16x32_f16(xhi, bl0, acc0, 0, 0, 0);
            acc1 = __builtin_amdgcn_mfma_f32_16x16x32_f16(xhi, bl1, acc1, 0, 0, 0);
        }

        // ---- flag-hint spin: wave wv's 16 producers (logical) ----
        {
            const int* fp = flags + ((t & 1) * NWG + (bg << 6) + (wv << 4)
                                     + (lane & 15)) * FSTRIDE;
            int spins = 0;
            for (;;) {
                int f = __hip_atomic_load(fp, __ATOMIC_RELAXED,
                                          __HIP_MEMORY_SCOPE_AGENT);
                if (__all(f >= t)) break;
                if (++spins > 4096) break;      // hint only; tags are the truth
                __builtin_amdgcn_s_sleep(1);
            }
        }

        // leader refreshes this XCD's L2 view (buffer_inv) before loads
        if (leader) __builtin_amdgcn_fence(__ATOMIC_ACQUIRE, "agent");

        // lane's h base in BYTES: batch row = 4096 B, wave k = 1024 B, quad = 16 B
        const u64 hb = (u64)hrd + ((u64)(b0 + lm) << 12) + (wv << 10) + (quad << 4);

        // ---- 16 fragment loads, L2-cached (sc0: L1-bypass only) ----
        u32x4 v[16];
        #pragma unroll
        for (int ks = 0; ks < 16; ks++) {
            asm volatile("global_load_dwordx4 %0, %1, off sc0"
                         : "=&v"(v[ks]) : "v"(hb + (u64)(ks * 64)));
        }
        asm volatile("s_waitcnt vmcnt(0)" ::: "memory");

        // ---- validate tags (dwords 0,2 cover both u64 stores per 16B);
        //      retry via L2; escalate to L2-bypass after 8 rounds ----
        int rounds = 0;
        for (;;) {
            u32 bad = 0;
            #pragma unroll
            for (int ks = 0; ks < 16; ks++) {
                bad |= (v[ks][0] & TAG32) ^ E32;   // u64 store #0 (dwords 0,1)
                bad |= (v[ks][2] & TAG32) ^ E32;   // u64 store #1 (dwords 2,3)
            }
            if (__all(bad == 0)) break;
            ++rounds;
            if (leader) __builtin_amdgcn_fence(__ATOMIC_ACQUIRE, "agent");
            if (bad) {                       // only stale lanes re-load
                __builtin_amdgcn_s_sleep(1);
                if (rounds < 8) {
                    #pragma unroll
                    for (int ks = 0; ks < 16; ks++) {
                        asm volatile("global_load_dwordx4 %0, %1, off sc0"
                                     : "=&v"(v[ks]) : "v"(hb + (u64)(ks * 64)));
                    }
                } else {                     // safety valve: coherence point
                    #pragma unroll
                    for (int ks = 0; ks < 16; ks++) {
                        asm volatile("global_load_dwordx4 %0, %1, off sc0 sc1"
                                     : "=&v"(v[ks]) : "v"(hb + (u64)(ks * 64)));
                    }
                }
            }
            asm volatile("s_waitcnt vmcnt(0)" ::: "memory");
        }

        // ---- h_{t-1} @ W_res^T: LSB-clear -> A-fragment, 32 MFMAs ----
        {
            const f16* w0 = Wr + lm * WPAD + wv * 512 + quad * 8;
            const f16* w1 = Wr + (lm + 16) * WPAD + wv * 512 + quad * 8;
            #pragma unroll
            for (int ks = 0; ks < 16; ks++) {
                f16x8 af;
                #pragma unroll
                for (int e = 0; e < 4; e++)
                    ((u32*)&af)[e] = v[ks][e] & ~TAG32;   // clear tag (<=1 ulp)
                f16x8 bf0 = *(const f16x8*)(w0 + ks * 32);   // LDS ds_read_b128
                f16x8 bf1 = *(const f16x8*)(w1 + ks * 32);
                acc0 = __builtin_amdgcn_mfma_f32_16x16x32_f16(af, bf0, acc0, 0, 0, 0);
                acc1 = __builtin_amdgcn_mfma_f32_16x16x32_f16(af, bf1, acc1, 0, 0, 0);
            }
        }

        // ---- per-wave partials to LDS (C/D layout: col=lane&15, row=quad*4+reg) ----
        {
            float* pw = part + wv * (BATS * PPAD);
            #pragma unroll
            for (int r = 0; r < 4; r++) {
                int m = quad * 4 + r;
                pw[m * PPAD + lm]      = acc0[r];
                pw[m * PPAD + 16 + lm] = acc1[r];
            }
        }
        __syncthreads();

        // ---- reduce 4 waves + tanh + store ----
        if (t == T_ - 1) {
            // final step: fp32 to out, 2 per thread (m = tid>>4, n = (tid&15)*2)
            const int m = tid >> 4;
            const int n = (tid & 15) * 2;
            const int o = m * PPAD + n;
            float s0 = part[o]     + part[BATS * PPAD + o]     + part[2 * BATS * PPAD + o]
                     + part[3 * BATS * PPAD + o];
            float s1 = part[o + 1] + part[BATS * PPAD + o + 1] + part[2 * BATS * PPAD + o + 1]
                     + part[3 * BATS * PPAD + o + 1];
            float* op = out + (size_t)(b0 + m) * H_ + r0 + n;
            op[0] = tanhf(s0);
            op[1] = tanhf(s1);
        } else if (tid < 128) {
            // h store: one u64 = 4 tagged halves per thread (m = tid>>3, n0 = (tid&7)*4)
            const int m  = tid >> 3;
            const int n0 = (tid & 7) * 4;
            const u16 bit = (u16)(((t + 1) >> 1) & 1);
            union { u16 h[4]; u64 u; } pk;
            #pragma unroll
            for (int e = 0; e < 4; e++) {
                const int o = m * PPAD + n0 + e;
                float s = part[o] + part[BATS * PPAD + o] + part[2 * BATS * PPAD + o]
                        + part[3 * BATS * PPAD + o];
                union { f16 f; u16 u; } cv;
                cv.f = (f16)tanhf(s);
                pk.h[e] = (u16)((cv.u & 0xFFFEu) | bit);   // mantissa LSB = tag
            }
            // fire-and-forget write-through to L3; validity is in-band
            __hip_atomic_store((u64*)(hwr + (size_t)(b0 + m) * H_ + r0 + n0),
                               pk.u, __ATOMIC_RELAXED, __HIP_MEMORY_SCOPE_AGENT);
        }

        // protect LDS partials from next step's writes; all h stores ISSUED
        __syncthreads();

        // ---- flag hint publish (after barrier => after all store issues) ----
        if (t < T_ - 1 && tid == 0) {
            __hip_atomic_store(flags + (((t + 1) & 1) * NWG + lid) * FSTRIDE,
                               t + 1, __ATOMIC_RELAXED, __HIP_MEMORY_SCOPE_AGENT);
        }
    }
}

extern "C" void kernel_launch(void* const* d_in, const int* in_sizes, int n_in,
                              void* d_out, int out_size, void* d_ws, size_t ws_size,
                              hipStream_t stream)
{
    (void)in_sizes; (void)n_in; (void)out_size; (void)ws_size;
    const float* x    = (const float*)d_in[0];
    const float* Win  = (const float*)d_in[1];
    const float* Wres = (const float*)d_in[2];
    float* out = (float*)d_out;

    u16* ht0 = (u16*)d_ws;                        // [64][2048] fp16, LSB = tag
    u16* ht1 = ht0 + (size_t)B_ * H_;
    int* flags = (int*)((char*)d_ws + (size_t)2 * B_ * H_ * sizeof(u16));

    // buffer0: 0x00 -> h_0 = 0, tag 0 fresh for t=0; buffer1: 0x01 -> stale
    // until real h_1; flags: 0 (step-0 spin passes: 0 >= 0).
    hipMemsetAsync(d_ws, 0x00, (size_t)B_ * H_ * sizeof(u16), stream);
    hipMemsetAsync((char*)d_ws + (size_t)B_ * H_ * sizeof(u16), 0x01,
                   (size_t)B_ * H_ * sizeof(u16), stream);
    hipMemsetAsync(flags, 0, (size_t)2 * NWG * FSTRIDE * sizeof(int), stream);

    hipFuncSetAttribute((const void*)esn_kernel,
                        hipFuncAttributeMaxDynamicSharedMemorySize, LDS_TOTAL);

    void* args[] = {(void*)&x, (void*)&Win, (void*)&Wres, (void*)&out,
                    (void*)&ht0, (void*)&ht1, (void*)&flags};
    // Coop launch (80-VGPR kernel: succeeded in R5). Return-check fallback is
    // zero-risk insurance (never fires when coop succeeds): grid = 256 = #CUs
    // => all WGs co-resident under a plain launch too.
    hipError_t ce = hipLaunchCooperativeKernel((const void*)esn_kernel,
                                               dim3(NWG), dim3(256),
                                               args, LDS_TOTAL, stream);
    if (ce != hipSuccess) {
        hipLaunchKernelGGL(esn_kernel, dim3(NWG), dim3(256), LDS_TOTAL, stream,
                           x, Win, Wres, out, ht0, ht1, flags);
    }
}